// Round 16
// baseline (57.030 us; speedup 1.0000x reference)
//
#include <hip/hip_runtime.h>
#include <hip/hip_bf16.h>

// QuantumLayer: 8-qubit circuit, batch 65536.
// final = V*m; V = U(weights)*diag((-i)^popc(j)); m[b][j] = prod_q (bit? sin:cos)(x/2).
// W (fp16): [Re V; Im V] 512x256 [r][k], built in-kernel via TRANSPOSED phase-1
// (row bid per block, coalesced writes — r15-validated). GEMM: 32x32x16 MFMA,
// wave's 32 W-rows resident; m-image in LDS; in-lane p + subset-sum sign tree.
//
// r16 vs r15 (56us, MfmaUtil 11%, conflicts 2.36M):
//  * A-image swizzle widened (row&7)<<4 -> (row&31)<<4: 32 rows now hit 32
//    DISTINCT 16B slots per read -> kills the inherent 4-way ds_read conflict.
//    (write side stays bijective: 32 octets of a row cover 32 slots).
//  * the two 32x32 tiles interleaved: 2 independent MFMA chains/wave (2x ILP),
//    shared ds_read offsets ((32+s31)&31 == s31).

typedef _Float16 half8 __attribute__((ext_vector_type(8)));
typedef __fp16 fp16x2 __attribute__((ext_vector_type(2)));
typedef float f32x4 __attribute__((ext_vector_type(4)));
typedef float f32x16 __attribute__((ext_vector_type(16)));

__device__ _Float16 g_W[512 * 256];
// Grid barrier state (self-cleaning; validated r5-r15).
__device__ int g_ctr = 0;
__device__ int g_sense = 0;

#define NBLK 256
// LDS map (bytes)
#define A0_OFF  0        // fp16[64][256] m-image buf0, XOR-swizzled (32 KB)
#define A1_OFF  32768    // buf1                                     (32 KB)
#define P0_OFF  65536    // PART buf0: 16 waves x 2080B              (33.3 KB)
#define P1_OFF  98816    // PART buf1                                (33.3 KB)
#define PRM_OFF 65536    // phase-1 gate params float4[64] — overlaps P0 (pre-barrier only)
// total 132096

static __device__ __forceinline__ int f_as_i(float f) { union { float f; int i; } u; u.f = f; return u.i; }
static __device__ __forceinline__ float i_as_f(int i) { union { float f; int i; } u; u.i = i; return u.f; }

// Build m-image rows [32 samples][256 k] fp16 starting at LDS row `row0`.
// Full-width swizzle: slot = octet ^ (row&31).
static __device__ __forceinline__ void stage_a(char* smem, const float* x,
                                               int base_sample, int abase,
                                               int row0, int tid) {
    int sl = tid >> 5, oct = tid & 31;
    const float4* xp = (const float4*)(x + (base_sample + sl) * 8);
    float4 xa = xp[0], xb = xp[1];
    float cc[8], ss[8];
#pragma unroll
    for (int q = 0; q < 8; ++q) {
        float xv = 0.5f * (q < 4 ? xa[q] : xb[q - 4]);
        cc[q] = __cosf(xv);
        ss[q] = __sinf(xv);
    }
    // k = oct*8 + e; wire w <-> bit (7-w): oct bits 4..0 = wires 0..4, e = wires 5..7
    float f0 = (oct & 16) ? ss[0] : cc[0];
    float f1 = (oct & 8) ? ss[1] : cc[1];
    float f2 = (oct & 4) ? ss[2] : cc[2];
    float f3 = (oct & 2) ? ss[3] : cc[3];
    float f4 = (oct & 1) ? ss[4] : cc[4];
    float P5 = f0 * f1 * f2 * f3 * f4;
    float u0 = P5 * (cc[5] * cc[6]), u1 = P5 * (cc[5] * ss[6]);
    float u2 = P5 * (ss[5] * cc[6]), u3 = P5 * (ss[5] * ss[6]);
    union { half8 h8; fp16x2 h2[4]; } w;
    w.h2[0] = __builtin_amdgcn_cvt_pkrtz(u0 * cc[7], u0 * ss[7]);
    w.h2[1] = __builtin_amdgcn_cvt_pkrtz(u1 * cc[7], u1 * ss[7]);
    w.h2[2] = __builtin_amdgcn_cvt_pkrtz(u2 * cc[7], u2 * ss[7]);
    w.h2[3] = __builtin_amdgcn_cvt_pkrtz(u3 * cc[7], u3 * ss[7]);
    int row = row0 + sl;
    *(half8*)(smem + abase + row * 512 + ((oct * 16) ^ ((row & 31) << 4))) = w.h8;
}

// Epilogue for one 32x32 tile: p in-lane, subset-sum sign tree, cross-hi shfl.
static __device__ __forceinline__ void epilogue(f32x16 acc, int row, char* smem,
                                                int pbase, int wv, int hi) {
    float p0 = acc[0] * acc[0] + acc[8] * acc[8];
    float p1 = acc[1] * acc[1] + acc[9] * acc[9];
    float p2 = acc[2] * acc[2] + acc[10] * acc[10];
    float p3 = acc[3] * acc[3] + acc[11] * acc[11];
    float p4 = acc[4] * acc[4] + acc[12] * acc[12];
    float p5 = acc[5] * acc[5] + acc[13] * acc[13];
    float p6 = acc[6] * acc[6] + acc[14] * acc[14];
    float p7 = acc[7] * acc[7] + acc[15] * acc[15];
    float a01 = p0 + p1, a23 = p2 + p3, a45 = p4 + p5, a67 = p6 + p7;
    float b03 = a01 + a23, b47 = a45 + a67;
    float S = b03 + b47;
    float E[8];
    E[0] = ((wv >> 3) & 1) ? -S : S;
    E[1] = ((wv >> 2) & 1) ? -S : S;
    E[2] = ((wv >> 1) & 1) ? -S : S;
    E[3] = (wv & 1) ? -S : S;
    E[4] = b03 - b47;
    E[5] = hi ? -S : S;
    E[6] = (a01 - a23) + (a45 - a67);
    E[7] = (p0 - p1) + (p2 - p3) + ((p4 - p5) + (p6 - p7));
#pragma unroll
    for (int q = 0; q < 8; ++q)
        E[q] += __shfl_xor(E[q], 32, 64);
    if (hi == 0) {
        *(f32x4*)(smem + pbase + wv * 2080 + row * 32) = (f32x4){E[0], E[1], E[2], E[3]};
        *(f32x4*)(smem + pbase + wv * 2080 + row * 32 + 16) = (f32x4){E[4], E[5], E[6], E[7]};
    }
}

__global__ __launch_bounds__(1024) void fused(const float* __restrict__ x,
                                              const float* __restrict__ wt,
                                              float* __restrict__ out) {
    __shared__ __align__(16) char smem[132096];
    const int tid = threadIdx.x;
    const int bid = blockIdx.x;
    const int wv = tid >> 6;
    const int lane = tid & 63;
    const int s31 = lane & 31;    // sample col / W-row-in-set
    const int hi = lane >> 5;     // k-half

    // ---------------- phase 1 (TRANSPOSED, r15-validated): row `bid` of V ----
    if (wv == 0) {
        {
            float2 w2 = *(const float2*)(wt + 2 * lane);
            float4 pr;
            pr.x = __cosf(0.5f * w2.x);
            pr.y = __sinf(0.5f * w2.x);
            pr.z = __cosf(0.5f * w2.y);
            pr.w = __sinf(0.5f * w2.y);
            *(float4*)(smem + PRM_OFF + lane * 16) = pr;
        }
        int jm[4];
#pragma unroll
        for (int u = 0; u < 4; ++u) {
            int j = u * 64 + lane;
#pragma unroll
            for (int q = 0; q < 8; ++q) {
                int cm = 1 << (7 - q);
                int tm = 1 << (7 - ((q + 1) & 7));
                j = (j & cm) ? (j ^ tm) : j;
            }
            jm[u] = j;
        }
        float2 a[4];   // amps i = u*64 + lane
#pragma unroll
        for (int u = 0; u < 4; ++u)
            a[u] = make_float2((u * 64 + lane) == bid ? 1.f : 0.f, 0.f);

        for (int lyr = 7; lyr >= 0; --lyr) {
            {
                float2 nv[4];
#pragma unroll
                for (int u = 0; u < 4; ++u) {
                    int bl = (jm[u] & 63) << 2;
                    int js = jm[u] >> 6;
                    float sx0 = i_as_f(__builtin_amdgcn_ds_bpermute(bl, f_as_i(a[0].x)));
                    float sx1 = i_as_f(__builtin_amdgcn_ds_bpermute(bl, f_as_i(a[1].x)));
                    float sx2 = i_as_f(__builtin_amdgcn_ds_bpermute(bl, f_as_i(a[2].x)));
                    float sx3 = i_as_f(__builtin_amdgcn_ds_bpermute(bl, f_as_i(a[3].x)));
                    float sy0 = i_as_f(__builtin_amdgcn_ds_bpermute(bl, f_as_i(a[0].y)));
                    float sy1 = i_as_f(__builtin_amdgcn_ds_bpermute(bl, f_as_i(a[1].y)));
                    float sy2 = i_as_f(__builtin_amdgcn_ds_bpermute(bl, f_as_i(a[2].y)));
                    float sy3 = i_as_f(__builtin_amdgcn_ds_bpermute(bl, f_as_i(a[3].y)));
                    nv[u].x = (js == 0) ? sx0 : (js == 1) ? sx1 : (js == 2) ? sx2 : sx3;
                    nv[u].y = (js == 0) ? sy0 : (js == 1) ? sy1 : (js == 2) ? sy2 : sy3;
                }
#pragma unroll
                for (int u = 0; u < 4; ++u) a[u] = nv[u];
            }
#pragma unroll
            for (int q = 0; q < 8; ++q) {
                float4 pr4 = *(const float4*)(smem + PRM_OFF + (lyr * 8 + q) * 16);
                float cy = pr4.x, sy = pr4.y, ezr = pr4.z, ezi = pr4.w;
                const int mask = 1 << (7 - q);
                float2 b[4];
                bool hb[4];
                if (mask == 128) {
                    b[0] = a[2]; b[1] = a[3]; b[2] = a[0]; b[3] = a[1];
                    hb[0] = false; hb[1] = false; hb[2] = true; hb[3] = true;
                } else if (mask == 64) {
                    b[0] = a[1]; b[1] = a[0]; b[2] = a[3]; b[3] = a[2];
                    hb[0] = false; hb[1] = true; hb[2] = false; hb[3] = true;
                } else {
#pragma unroll
                    for (int u = 0; u < 4; ++u) {
                        b[u].x = __shfl_xor(a[u].x, mask, 64);
                        b[u].y = __shfl_xor(a[u].y, mask, 64);
                        hb[u] = (lane & mask) != 0;
                    }
                }
#pragma unroll
                for (int u = 0; u < 4; ++u) {
                    float pa = hb[u] ? ezi : -ezi;
                    float ax = a[u].x * ezr - a[u].y * pa;
                    float ay = a[u].x * pa + a[u].y * ezr;
                    float bx = b[u].x * ezr + b[u].y * pa;
                    float by = -b[u].x * pa + b[u].y * ezr;
                    float sg = hb[u] ? -sy : sy;     // RY(-θy)
                    a[u] = make_float2(cy * ax + sg * bx, cy * ay + sg * by);
                }
            }
        }
#pragma unroll
        for (int u = 0; u < 4; ++u) {
            int j = u * 64 + lane;
            int pc = __popc(j) & 3;
            float pr = (pc == 0) ? 1.f : (pc == 2) ? -1.f : 0.f;
            float pim = (pc == 1) ? -1.f : (pc == 3) ? 1.f : 0.f;
            g_W[bid * 256 + j] = (_Float16)(a[u].x * pr - a[u].y * pim);
            g_W[(256 + bid) * 256 + j] = (_Float16)(a[u].x * pim + a[u].y * pr);
        }
    }

    // ---- stage_a(group 0): hoisted BEFORE grid barrier (idle-wave overlap) ----
    stage_a(smem, x, bid * 256, A0_OFF, 0, tid);
    stage_a(smem, x, bid * 256 + 32, A0_OFF, 32, tid);

    // ---------------- grid barrier (sense-reversing, validated r5-r15) ------
    __syncthreads();
    if (tid == 0) {
        __threadfence();
        int my_sense = __hip_atomic_load(&g_sense, __ATOMIC_RELAXED,
                                         __HIP_MEMORY_SCOPE_AGENT) ^ 1;
        int arrived = __hip_atomic_fetch_add(&g_ctr, 1, __ATOMIC_ACQ_REL,
                                             __HIP_MEMORY_SCOPE_AGENT) + 1;
        if (arrived == NBLK) {
            __hip_atomic_store(&g_ctr, 0, __ATOMIC_RELAXED,
                               __HIP_MEMORY_SCOPE_AGENT);
            __hip_atomic_store(&g_sense, my_sense, __ATOMIC_RELEASE,
                               __HIP_MEMORY_SCOPE_AGENT);
        } else {
            while (__hip_atomic_load(&g_sense, __ATOMIC_RELAXED,
                                     __HIP_MEMORY_SCOPE_AGENT) != my_sense) {
                __builtin_amdgcn_s_sleep(8);
            }
            (void)__hip_atomic_load(&g_sense, __ATOMIC_ACQUIRE,
                                    __HIP_MEMORY_SCOPE_AGENT);
        }
        __threadfence();
    }
    __syncthreads();

    // ---------------- A-operand: 32 W-rows per wave (r12 layout) ------------
    half8 wfr[16];
    {
        int grow = ((s31 >> 4) * 256) + wv * 16 + (s31 & 15);
        const _Float16* wp = &g_W[grow * 256 + hi * 8];
#pragma unroll
        for (int t = 0; t < 16; ++t)
            wfr[t] = *(const half8*)(wp + t * 16);
    }

    // ---------------- main loop: 4 groups x 64 samples, 1 barrier/group -----
    for (int g = 0; g < 4; ++g) {
        const int abase = (g & 1) ? A1_OFF : A0_OFF;
        const int pbase = (g & 1) ? P1_OFF : P0_OFF;

        if (g < 3) {
            const int nbase = (g & 1) ? A0_OFF : A1_OFF;
            stage_a(smem, x, bid * 256 + (g + 1) * 64, nbase, 0, tid);
            stage_a(smem, x, bid * 256 + (g + 1) * 64 + 32, nbase, 32, tid);
        }

        // ---- two 32x32 tiles INTERLEAVED (independent acc chains, 2x ILP) ----
        // swizzle note: (32+s31)&31 == s31 -> both tiles share read offsets.
        const int rowb0 = abase + s31 * 512;
        const int rowb1 = abase + (32 + s31) * 512;
        const int swz = (s31 & 31) << 4;
        f32x16 acc0 = {0.f, 0.f, 0.f, 0.f, 0.f, 0.f, 0.f, 0.f,
                       0.f, 0.f, 0.f, 0.f, 0.f, 0.f, 0.f, 0.f};
        f32x16 acc1 = acc0;
#pragma unroll
        for (int t = 0; t < 16; ++t) {
            const int off = (t * 32 + hi * 16) ^ swz;
            half8 b0 = *(const half8*)(smem + rowb0 + off);
            half8 b1 = *(const half8*)(smem + rowb1 + off);
            acc0 = __builtin_amdgcn_mfma_f32_32x32x16_f16(wfr[t], b0, acc0, 0, 0, 0);
            acc1 = __builtin_amdgcn_mfma_f32_32x32x16_f16(wfr[t], b1, acc1, 0, 0, 0);
        }
        epilogue(acc0, s31, smem, pbase, wv, hi);
        epilogue(acc1, 32 + s31, smem, pbase, wv, hi);

        __syncthreads();   // PART[g&1] ready AND A[(g+1)&1] ready

        // ---- cross-wave sum + store (overlaps next section) ----
        if (tid < 512) {
            int s2 = tid >> 3, q = tid & 7;
            const char* pb = smem + pbase + s2 * 32 + q * 4;
            float sum = 0.f;
#pragma unroll
            for (int w = 0; w < 16; ++w)
                sum += *(const float*)(pb + w * 2080);
            out[(bid * 256 + g * 64 + s2) * 8 + q] = sum;
        }
    }
}

extern "C" void kernel_launch(void* const* d_in, const int* in_sizes, int n_in,
                              void* d_out, int out_size, void* d_ws, size_t ws_size,
                              hipStream_t stream) {
    const float* x = (const float*)d_in[0];       // (65536, 8) f32
    const float* wt = (const float*)d_in[1];      // (8, 8, 2) f32
    float* out = (float*)d_out;                   // (65536, 8) f32
    (void)d_ws; (void)ws_size; (void)in_sizes; (void)n_in; (void)out_size;

    fused<<<NBLK, 1024, 0, stream>>>(x, wt, out);
}

// Round 18
// 55.216 us; speedup vs baseline: 1.0329x; 1.0329x over previous
//
#include <hip/hip_runtime.h>
#include <hip/hip_bf16.h>

// QuantumLayer: 8-qubit circuit, batch 65536.
// final = V*m; V = U(weights)*diag((-i)^popc(j)); m[b][j] = prod_q (bit? sin:cos)(x/2).
// W (fp16): [Re V; Im V] 512x256 [r][k], built in-kernel via TRANSPOSED phase-1
// (row bid per block, coalesced writes — r15-validated). GEMM: 32x32x16 MFMA,
// wave's 32 W-rows resident; m-image in LDS; in-lane p + subset-sum sign tree.
//
// r18 = r15 (best passing, 55.4us) + r16's full-width swizzle ONLY:
//  * A-image swizzle (row&7)<<4 -> (row&31)<<4 (conflicts 2.36M -> 262K, the
//    one r16 change that verifiably worked).
//  * tiles stay SEQUENTIAL (r16's interleave caused scratch spills: dual f32x16
//    + wfr[16] > budget; WRITE_SIZE 2.3->6.4MB ate the win).
//  * NBLK=256 strictly (r17: 512-block barrier deadlocked — VGPR>64 means only
//    1 block/CU resident; W-residency hard-caps occupancy at 16 waves/CU).

typedef _Float16 half8 __attribute__((ext_vector_type(8)));
typedef __fp16 fp16x2 __attribute__((ext_vector_type(2)));
typedef float f32x4 __attribute__((ext_vector_type(4)));
typedef float f32x16 __attribute__((ext_vector_type(16)));

__device__ _Float16 g_W[512 * 256];
// Grid barrier state (self-cleaning; validated r5-r16).
__device__ int g_ctr = 0;
__device__ int g_sense = 0;

#define NBLK 256
// LDS map (bytes)
#define A0_OFF  0        // fp16[64][256] m-image buf0, XOR-swizzled (32 KB)
#define A1_OFF  32768    // buf1                                     (32 KB)
#define P0_OFF  65536    // PART buf0: 16 waves x 2080B              (33.3 KB)
#define P1_OFF  98816    // PART buf1                                (33.3 KB)
#define PRM_OFF 65536    // phase-1 gate params float4[64] — overlaps P0 (pre-barrier only)
// total 132096

static __device__ __forceinline__ int f_as_i(float f) { union { float f; int i; } u; u.f = f; return u.i; }
static __device__ __forceinline__ float i_as_f(int i) { union { float f; int i; } u; u.i = i; return u.f; }

// Build m-image rows [32 samples][256 k] fp16 starting at LDS row `row0`.
// Full-width swizzle: slot = octet ^ (row&31).
static __device__ __forceinline__ void stage_a(char* smem, const float* x,
                                               int base_sample, int abase,
                                               int row0, int tid) {
    int sl = tid >> 5, oct = tid & 31;
    const float4* xp = (const float4*)(x + (base_sample + sl) * 8);
    float4 xa = xp[0], xb = xp[1];
    float cc[8], ss[8];
#pragma unroll
    for (int q = 0; q < 8; ++q) {
        float xv = 0.5f * (q < 4 ? xa[q] : xb[q - 4]);
        cc[q] = __cosf(xv);
        ss[q] = __sinf(xv);
    }
    // k = oct*8 + e; wire w <-> bit (7-w): oct bits 4..0 = wires 0..4, e = wires 5..7
    float f0 = (oct & 16) ? ss[0] : cc[0];
    float f1 = (oct & 8) ? ss[1] : cc[1];
    float f2 = (oct & 4) ? ss[2] : cc[2];
    float f3 = (oct & 2) ? ss[3] : cc[3];
    float f4 = (oct & 1) ? ss[4] : cc[4];
    float P5 = f0 * f1 * f2 * f3 * f4;
    float u0 = P5 * (cc[5] * cc[6]), u1 = P5 * (cc[5] * ss[6]);
    float u2 = P5 * (ss[5] * cc[6]), u3 = P5 * (ss[5] * ss[6]);
    union { half8 h8; fp16x2 h2[4]; } w;
    w.h2[0] = __builtin_amdgcn_cvt_pkrtz(u0 * cc[7], u0 * ss[7]);
    w.h2[1] = __builtin_amdgcn_cvt_pkrtz(u1 * cc[7], u1 * ss[7]);
    w.h2[2] = __builtin_amdgcn_cvt_pkrtz(u2 * cc[7], u2 * ss[7]);
    w.h2[3] = __builtin_amdgcn_cvt_pkrtz(u3 * cc[7], u3 * ss[7]);
    int row = row0 + sl;
    *(half8*)(smem + abase + row * 512 + ((oct * 16) ^ ((row & 31) << 4))) = w.h8;
}

__global__ __launch_bounds__(1024) void fused(const float* __restrict__ x,
                                              const float* __restrict__ wt,
                                              float* __restrict__ out) {
    __shared__ __align__(16) char smem[132096];
    const int tid = threadIdx.x;
    const int bid = blockIdx.x;
    const int wv = tid >> 6;
    const int lane = tid & 63;
    const int s31 = lane & 31;    // sample col / W-row-in-set
    const int hi = lane >> 5;     // k-half

    // ---------------- phase 1 (TRANSPOSED, r15-validated): row `bid` of V ----
    if (wv == 0) {
        {
            float2 w2 = *(const float2*)(wt + 2 * lane);
            float4 pr;
            pr.x = __cosf(0.5f * w2.x);
            pr.y = __sinf(0.5f * w2.x);
            pr.z = __cosf(0.5f * w2.y);
            pr.w = __sinf(0.5f * w2.y);
            *(float4*)(smem + PRM_OFF + lane * 16) = pr;
        }
        int jm[4];
#pragma unroll
        for (int u = 0; u < 4; ++u) {
            int j = u * 64 + lane;
#pragma unroll
            for (int q = 0; q < 8; ++q) {
                int cm = 1 << (7 - q);
                int tm = 1 << (7 - ((q + 1) & 7));
                j = (j & cm) ? (j ^ tm) : j;
            }
            jm[u] = j;
        }
        float2 a[4];   // amps i = u*64 + lane
#pragma unroll
        for (int u = 0; u < 4; ++u)
            a[u] = make_float2((u * 64 + lane) == bid ? 1.f : 0.f, 0.f);

        for (int lyr = 7; lyr >= 0; --lyr) {
            {
                float2 nv[4];
#pragma unroll
                for (int u = 0; u < 4; ++u) {
                    int bl = (jm[u] & 63) << 2;
                    int js = jm[u] >> 6;
                    float sx0 = i_as_f(__builtin_amdgcn_ds_bpermute(bl, f_as_i(a[0].x)));
                    float sx1 = i_as_f(__builtin_amdgcn_ds_bpermute(bl, f_as_i(a[1].x)));
                    float sx2 = i_as_f(__builtin_amdgcn_ds_bpermute(bl, f_as_i(a[2].x)));
                    float sx3 = i_as_f(__builtin_amdgcn_ds_bpermute(bl, f_as_i(a[3].x)));
                    float sy0 = i_as_f(__builtin_amdgcn_ds_bpermute(bl, f_as_i(a[0].y)));
                    float sy1 = i_as_f(__builtin_amdgcn_ds_bpermute(bl, f_as_i(a[1].y)));
                    float sy2 = i_as_f(__builtin_amdgcn_ds_bpermute(bl, f_as_i(a[2].y)));
                    float sy3 = i_as_f(__builtin_amdgcn_ds_bpermute(bl, f_as_i(a[3].y)));
                    nv[u].x = (js == 0) ? sx0 : (js == 1) ? sx1 : (js == 2) ? sx2 : sx3;
                    nv[u].y = (js == 0) ? sy0 : (js == 1) ? sy1 : (js == 2) ? sy2 : sy3;
                }
#pragma unroll
                for (int u = 0; u < 4; ++u) a[u] = nv[u];
            }
#pragma unroll
            for (int q = 0; q < 8; ++q) {
                float4 pr4 = *(const float4*)(smem + PRM_OFF + (lyr * 8 + q) * 16);
                float cy = pr4.x, sy = pr4.y, ezr = pr4.z, ezi = pr4.w;
                const int mask = 1 << (7 - q);
                float2 b[4];
                bool hb[4];
                if (mask == 128) {
                    b[0] = a[2]; b[1] = a[3]; b[2] = a[0]; b[3] = a[1];
                    hb[0] = false; hb[1] = false; hb[2] = true; hb[3] = true;
                } else if (mask == 64) {
                    b[0] = a[1]; b[1] = a[0]; b[2] = a[3]; b[3] = a[2];
                    hb[0] = false; hb[1] = true; hb[2] = false; hb[3] = true;
                } else {
#pragma unroll
                    for (int u = 0; u < 4; ++u) {
                        b[u].x = __shfl_xor(a[u].x, mask, 64);
                        b[u].y = __shfl_xor(a[u].y, mask, 64);
                        hb[u] = (lane & mask) != 0;
                    }
                }
#pragma unroll
                for (int u = 0; u < 4; ++u) {
                    float pa = hb[u] ? ezi : -ezi;
                    float ax = a[u].x * ezr - a[u].y * pa;
                    float ay = a[u].x * pa + a[u].y * ezr;
                    float bx = b[u].x * ezr + b[u].y * pa;
                    float by = -b[u].x * pa + b[u].y * ezr;
                    float sg = hb[u] ? -sy : sy;     // RY(-θy)
                    a[u] = make_float2(cy * ax + sg * bx, cy * ay + sg * by);
                }
            }
        }
#pragma unroll
        for (int u = 0; u < 4; ++u) {
            int j = u * 64 + lane;
            int pc = __popc(j) & 3;
            float pr = (pc == 0) ? 1.f : (pc == 2) ? -1.f : 0.f;
            float pim = (pc == 1) ? -1.f : (pc == 3) ? 1.f : 0.f;
            g_W[bid * 256 + j] = (_Float16)(a[u].x * pr - a[u].y * pim);
            g_W[(256 + bid) * 256 + j] = (_Float16)(a[u].x * pim + a[u].y * pr);
        }
    }

    // ---- stage_a(group 0): hoisted BEFORE grid barrier (idle-wave overlap) ----
    stage_a(smem, x, bid * 256, A0_OFF, 0, tid);
    stage_a(smem, x, bid * 256 + 32, A0_OFF, 32, tid);

    // ---------------- grid barrier (sense-reversing, validated r5-r16) ------
    __syncthreads();
    if (tid == 0) {
        __threadfence();
        int my_sense = __hip_atomic_load(&g_sense, __ATOMIC_RELAXED,
                                         __HIP_MEMORY_SCOPE_AGENT) ^ 1;
        int arrived = __hip_atomic_fetch_add(&g_ctr, 1, __ATOMIC_ACQ_REL,
                                             __HIP_MEMORY_SCOPE_AGENT) + 1;
        if (arrived == NBLK) {
            __hip_atomic_store(&g_ctr, 0, __ATOMIC_RELAXED,
                               __HIP_MEMORY_SCOPE_AGENT);
            __hip_atomic_store(&g_sense, my_sense, __ATOMIC_RELEASE,
                               __HIP_MEMORY_SCOPE_AGENT);
        } else {
            while (__hip_atomic_load(&g_sense, __ATOMIC_RELAXED,
                                     __HIP_MEMORY_SCOPE_AGENT) != my_sense) {
                __builtin_amdgcn_s_sleep(8);
            }
            (void)__hip_atomic_load(&g_sense, __ATOMIC_ACQUIRE,
                                    __HIP_MEMORY_SCOPE_AGENT);
        }
        __threadfence();
    }
    __syncthreads();

    // ---------------- A-operand: 32 W-rows per wave (r12 layout) ------------
    half8 wfr[16];
    {
        int grow = ((s31 >> 4) * 256) + wv * 16 + (s31 & 15);
        const _Float16* wp = &g_W[grow * 256 + hi * 8];
#pragma unroll
        for (int t = 0; t < 16; ++t)
            wfr[t] = *(const half8*)(wp + t * 16);
    }

    // ---------------- main loop: 4 groups x 64 samples, 1 barrier/group -----
    for (int g = 0; g < 4; ++g) {
        const int abase = (g & 1) ? A1_OFF : A0_OFF;
        const int pbase = (g & 1) ? P1_OFF : P0_OFF;

        if (g < 3) {
            const int nbase = (g & 1) ? A0_OFF : A1_OFF;
            stage_a(smem, x, bid * 256 + (g + 1) * 64, nbase, 0, tid);
            stage_a(smem, x, bid * 256 + (g + 1) * 64 + 32, nbase, 32, tid);
        }

        // ---- two 32x32 tiles SEQUENTIAL (r15; r16's interleave spilled) ----
#pragma unroll
        for (int t2 = 0; t2 < 2; ++t2) {
            const int row = t2 * 32 + s31;
            const int rowb = abase + row * 512;
            const int swz = (row & 31) << 4;   // full-width swizzle (r16)
            f32x16 acc = {0.f, 0.f, 0.f, 0.f, 0.f, 0.f, 0.f, 0.f,
                          0.f, 0.f, 0.f, 0.f, 0.f, 0.f, 0.f, 0.f};
#pragma unroll
            for (int t = 0; t < 16; ++t) {
                half8 bfr = *(const half8*)(smem + rowb + ((t * 32 + hi * 16) ^ swz));
                acc = __builtin_amdgcn_mfma_f32_32x32x16_f16(wfr[t], bfr, acc, 0, 0, 0);
            }

            // ---- epilogue: p in-lane, subset-sum sign reduce, cross-hi shfl ----
            float p0 = acc[0] * acc[0] + acc[8] * acc[8];
            float p1 = acc[1] * acc[1] + acc[9] * acc[9];
            float p2 = acc[2] * acc[2] + acc[10] * acc[10];
            float p3 = acc[3] * acc[3] + acc[11] * acc[11];
            float p4 = acc[4] * acc[4] + acc[12] * acc[12];
            float p5 = acc[5] * acc[5] + acc[13] * acc[13];
            float p6 = acc[6] * acc[6] + acc[14] * acc[14];
            float p7 = acc[7] * acc[7] + acc[15] * acc[15];
            float a01 = p0 + p1, a23 = p2 + p3, a45 = p4 + p5, a67 = p6 + p7;
            float b03 = a01 + a23, b47 = a45 + a67;
            float S = b03 + b47;
            float E[8];
            E[0] = ((wv >> 3) & 1) ? -S : S;
            E[1] = ((wv >> 2) & 1) ? -S : S;
            E[2] = ((wv >> 1) & 1) ? -S : S;
            E[3] = (wv & 1) ? -S : S;
            E[4] = b03 - b47;
            E[5] = hi ? -S : S;
            E[6] = (a01 - a23) + (a45 - a67);
            E[7] = (p0 - p1) + (p2 - p3) + ((p4 - p5) + (p6 - p7));
#pragma unroll
            for (int q = 0; q < 8; ++q)
                E[q] += __shfl_xor(E[q], 32, 64);
            if (hi == 0) {
                *(f32x4*)(smem + pbase + wv * 2080 + row * 32) = (f32x4){E[0], E[1], E[2], E[3]};
                *(f32x4*)(smem + pbase + wv * 2080 + row * 32 + 16) = (f32x4){E[4], E[5], E[6], E[7]};
            }
        }
        __syncthreads();   // PART[g&1] ready AND A[(g+1)&1] ready

        // ---- cross-wave sum + store (overlaps next section) ----
        if (tid < 512) {
            int s2 = tid >> 3, q = tid & 7;
            const char* pb = smem + pbase + s2 * 32 + q * 4;
            float sum = 0.f;
#pragma unroll
            for (int w = 0; w < 16; ++w)
                sum += *(const float*)(pb + w * 2080);
            out[(bid * 256 + g * 64 + s2) * 8 + q] = sum;
        }
    }
}

extern "C" void kernel_launch(void* const* d_in, const int* in_sizes, int n_in,
                              void* d_out, int out_size, void* d_ws, size_t ws_size,
                              hipStream_t stream) {
    const float* x = (const float*)d_in[0];       // (65536, 8) f32
    const float* wt = (const float*)d_in[1];      // (8, 8, 2) f32
    float* out = (float*)d_out;                   // (65536, 8) f32
    (void)d_ws; (void)ws_size; (void)in_sizes; (void)n_in; (void)out_size;

    fused<<<NBLK, 1024, 0, stream>>>(x, wt, out);
}

// Round 19
// 55.050 us; speedup vs baseline: 1.0360x; 1.0030x over previous
//
#include <hip/hip_runtime.h>
#include <hip/hip_bf16.h>

// QuantumLayer: 8-qubit circuit, batch 65536.
// final = V*m; V = U(weights)*diag((-i)^popc(j)); m[b][j] = prod_q (bit? sin:cos)(x/2).
// W (fp16): [Re V; Im V] 512x256 [r][k], built in-kernel via TRANSPOSED phase-1
// (row bid per block, coalesced writes — r15). GEMM: 32x32x16 MFMA, wave's 32
// W-rows resident; m-image in LDS (full-width swizzle, r18); in-lane p +
// subset-sum sign tree epilogue.
//
// r19 vs r18 (55.2us): VALU-for-DS swaps on the two serial chains.
//  * cross-lane exchange: mask32 -> v_permlane32_swap (VALU), masks 1,2 -> DPP
//    quad_perm (VALU); only masks 4,8,16 remain ds-based. Phase-1 layer chain
//    8 DS hops -> 3.
//  * epilogue xor-32 reduce -> permlane32_swap (64 DS ops/wave removed).

typedef _Float16 half8 __attribute__((ext_vector_type(8)));
typedef __fp16 fp16x2 __attribute__((ext_vector_type(2)));
typedef float f32x4 __attribute__((ext_vector_type(4)));
typedef float f32x16 __attribute__((ext_vector_type(16)));
typedef int iv2 __attribute__((ext_vector_type(2)));

__device__ _Float16 g_W[512 * 256];
// Grid barrier state (self-cleaning; validated r5-r18).
__device__ int g_ctr = 0;
__device__ int g_sense = 0;

#define NBLK 256
// LDS map (bytes)
#define A0_OFF  0        // fp16[64][256] m-image buf0, XOR-swizzled (32 KB)
#define A1_OFF  32768    // buf1                                     (32 KB)
#define P0_OFF  65536    // PART buf0: 16 waves x 2080B              (33.3 KB)
#define P1_OFF  98816    // PART buf1                                (33.3 KB)
#define PRM_OFF 65536    // phase-1 gate params float4[64] — overlaps P0 (pre-barrier only)
// total 132096

static __device__ __forceinline__ int f_as_i(float f) { union { float f; int i; } u; u.f = f; return u.i; }
static __device__ __forceinline__ float i_as_f(int i) { union { float f; int i; } u; u.i = i; return u.f; }

// xor-32 partner via permlane32_swap (VALU): with a=b=v, new_a[i>=32]=v[i-32],
// new_b[i<32]=v[i+32]  ->  partner = (lane&32) ? r[0] : r[1].
static __device__ __forceinline__ float xor32(float v, int lane) {
    iv2 r = __builtin_amdgcn_permlane32_swap(f_as_i(v), f_as_i(v), false, false);
    return i_as_f((lane & 32) ? r[0] : r[1]);
}

// cross-lane exchange by compile-time-foldable mask (called from unrolled loops)
static __device__ __forceinline__ float lx(float v, int mask, int lane) {
    if (mask == 32) {
        return xor32(v, lane);
    } else if (mask == 2) {
        return i_as_f(__builtin_amdgcn_mov_dpp(f_as_i(v), 0x4E, 0xF, 0xF, true));  // quad_perm [2,3,0,1]
    } else if (mask == 1) {
        return i_as_f(__builtin_amdgcn_mov_dpp(f_as_i(v), 0xB1, 0xF, 0xF, true));  // quad_perm [1,0,3,2]
    } else {
        return __shfl_xor(v, mask, 64);
    }
}

// Build m-image rows [32 samples][256 k] fp16 starting at LDS row `row0`.
// Full-width swizzle: slot = octet ^ (row&31).
static __device__ __forceinline__ void stage_a(char* smem, const float* x,
                                               int base_sample, int abase,
                                               int row0, int tid) {
    int sl = tid >> 5, oct = tid & 31;
    const float4* xp = (const float4*)(x + (base_sample + sl) * 8);
    float4 xa = xp[0], xb = xp[1];
    float cc[8], ss[8];
#pragma unroll
    for (int q = 0; q < 8; ++q) {
        float xv = 0.5f * (q < 4 ? xa[q] : xb[q - 4]);
        cc[q] = __cosf(xv);
        ss[q] = __sinf(xv);
    }
    // k = oct*8 + e; wire w <-> bit (7-w): oct bits 4..0 = wires 0..4, e = wires 5..7
    float f0 = (oct & 16) ? ss[0] : cc[0];
    float f1 = (oct & 8) ? ss[1] : cc[1];
    float f2 = (oct & 4) ? ss[2] : cc[2];
    float f3 = (oct & 2) ? ss[3] : cc[3];
    float f4 = (oct & 1) ? ss[4] : cc[4];
    float P5 = f0 * f1 * f2 * f3 * f4;
    float u0 = P5 * (cc[5] * cc[6]), u1 = P5 * (cc[5] * ss[6]);
    float u2 = P5 * (ss[5] * cc[6]), u3 = P5 * (ss[5] * ss[6]);
    union { half8 h8; fp16x2 h2[4]; } w;
    w.h2[0] = __builtin_amdgcn_cvt_pkrtz(u0 * cc[7], u0 * ss[7]);
    w.h2[1] = __builtin_amdgcn_cvt_pkrtz(u1 * cc[7], u1 * ss[7]);
    w.h2[2] = __builtin_amdgcn_cvt_pkrtz(u2 * cc[7], u2 * ss[7]);
    w.h2[3] = __builtin_amdgcn_cvt_pkrtz(u3 * cc[7], u3 * ss[7]);
    int row = row0 + sl;
    *(half8*)(smem + abase + row * 512 + ((oct * 16) ^ ((row & 31) << 4))) = w.h8;
}

__global__ __launch_bounds__(1024) void fused(const float* __restrict__ x,
                                              const float* __restrict__ wt,
                                              float* __restrict__ out) {
    __shared__ __align__(16) char smem[132096];
    const int tid = threadIdx.x;
    const int bid = blockIdx.x;
    const int wv = tid >> 6;
    const int lane = tid & 63;
    const int s31 = lane & 31;    // sample col / W-row-in-set
    const int hi = lane >> 5;     // k-half

    // ---------------- phase 1 (TRANSPOSED, r15-validated): row `bid` of V ----
    if (wv == 0) {
        {
            float2 w2 = *(const float2*)(wt + 2 * lane);
            float4 pr;
            pr.x = __cosf(0.5f * w2.x);
            pr.y = __sinf(0.5f * w2.x);
            pr.z = __cosf(0.5f * w2.y);
            pr.w = __sinf(0.5f * w2.y);
            *(float4*)(smem + PRM_OFF + lane * 16) = pr;
        }
        int jm[4];
#pragma unroll
        for (int u = 0; u < 4; ++u) {
            int j = u * 64 + lane;
#pragma unroll
            for (int q = 0; q < 8; ++q) {
                int cm = 1 << (7 - q);
                int tm = 1 << (7 - ((q + 1) & 7));
                j = (j & cm) ? (j ^ tm) : j;
            }
            jm[u] = j;
        }
        float2 a[4];   // amps i = u*64 + lane
#pragma unroll
        for (int u = 0; u < 4; ++u)
            a[u] = make_float2((u * 64 + lane) == bid ? 1.f : 0.f, 0.f);

        for (int lyr = 7; lyr >= 0; --lyr) {
            {
                float2 nv[4];
#pragma unroll
                for (int u = 0; u < 4; ++u) {
                    int bl = (jm[u] & 63) << 2;
                    int js = jm[u] >> 6;
                    float sx0 = i_as_f(__builtin_amdgcn_ds_bpermute(bl, f_as_i(a[0].x)));
                    float sx1 = i_as_f(__builtin_amdgcn_ds_bpermute(bl, f_as_i(a[1].x)));
                    float sx2 = i_as_f(__builtin_amdgcn_ds_bpermute(bl, f_as_i(a[2].x)));
                    float sx3 = i_as_f(__builtin_amdgcn_ds_bpermute(bl, f_as_i(a[3].x)));
                    float sy0 = i_as_f(__builtin_amdgcn_ds_bpermute(bl, f_as_i(a[0].y)));
                    float sy1 = i_as_f(__builtin_amdgcn_ds_bpermute(bl, f_as_i(a[1].y)));
                    float sy2 = i_as_f(__builtin_amdgcn_ds_bpermute(bl, f_as_i(a[2].y)));
                    float sy3 = i_as_f(__builtin_amdgcn_ds_bpermute(bl, f_as_i(a[3].y)));
                    nv[u].x = (js == 0) ? sx0 : (js == 1) ? sx1 : (js == 2) ? sx2 : sx3;
                    nv[u].y = (js == 0) ? sy0 : (js == 1) ? sy1 : (js == 2) ? sy2 : sy3;
                }
#pragma unroll
                for (int u = 0; u < 4; ++u) a[u] = nv[u];
            }
#pragma unroll
            for (int q = 0; q < 8; ++q) {
                float4 pr4 = *(const float4*)(smem + PRM_OFF + (lyr * 8 + q) * 16);
                float cy = pr4.x, sy = pr4.y, ezr = pr4.z, ezi = pr4.w;
                const int mask = 1 << (7 - q);
                float2 b[4];
                bool hb[4];
                if (mask == 128) {
                    b[0] = a[2]; b[1] = a[3]; b[2] = a[0]; b[3] = a[1];
                    hb[0] = false; hb[1] = false; hb[2] = true; hb[3] = true;
                } else if (mask == 64) {
                    b[0] = a[1]; b[1] = a[0]; b[2] = a[3]; b[3] = a[2];
                    hb[0] = false; hb[1] = true; hb[2] = false; hb[3] = true;
                } else {
#pragma unroll
                    for (int u = 0; u < 4; ++u) {
                        b[u].x = lx(a[u].x, mask, lane);
                        b[u].y = lx(a[u].y, mask, lane);
                        hb[u] = (lane & mask) != 0;
                    }
                }
#pragma unroll
                for (int u = 0; u < 4; ++u) {
                    float pa = hb[u] ? ezi : -ezi;
                    float ax = a[u].x * ezr - a[u].y * pa;
                    float ay = a[u].x * pa + a[u].y * ezr;
                    float bx = b[u].x * ezr + b[u].y * pa;
                    float by = -b[u].x * pa + b[u].y * ezr;
                    float sg = hb[u] ? -sy : sy;     // RY(-θy)
                    a[u] = make_float2(cy * ax + sg * bx, cy * ay + sg * by);
                }
            }
        }
#pragma unroll
        for (int u = 0; u < 4; ++u) {
            int j = u * 64 + lane;
            int pc = __popc(j) & 3;
            float pr = (pc == 0) ? 1.f : (pc == 2) ? -1.f : 0.f;
            float pim = (pc == 1) ? -1.f : (pc == 3) ? 1.f : 0.f;
            g_W[bid * 256 + j] = (_Float16)(a[u].x * pr - a[u].y * pim);
            g_W[(256 + bid) * 256 + j] = (_Float16)(a[u].x * pim + a[u].y * pr);
        }
    }

    // ---- stage_a(group 0): hoisted BEFORE grid barrier (idle-wave overlap) ----
    stage_a(smem, x, bid * 256, A0_OFF, 0, tid);
    stage_a(smem, x, bid * 256 + 32, A0_OFF, 32, tid);

    // ---------------- grid barrier (sense-reversing, validated r5-r18) ------
    __syncthreads();
    if (tid == 0) {
        __threadfence();
        int my_sense = __hip_atomic_load(&g_sense, __ATOMIC_RELAXED,
                                         __HIP_MEMORY_SCOPE_AGENT) ^ 1;
        int arrived = __hip_atomic_fetch_add(&g_ctr, 1, __ATOMIC_ACQ_REL,
                                             __HIP_MEMORY_SCOPE_AGENT) + 1;
        if (arrived == NBLK) {
            __hip_atomic_store(&g_ctr, 0, __ATOMIC_RELAXED,
                               __HIP_MEMORY_SCOPE_AGENT);
            __hip_atomic_store(&g_sense, my_sense, __ATOMIC_RELEASE,
                               __HIP_MEMORY_SCOPE_AGENT);
        } else {
            while (__hip_atomic_load(&g_sense, __ATOMIC_RELAXED,
                                     __HIP_MEMORY_SCOPE_AGENT) != my_sense) {
                __builtin_amdgcn_s_sleep(8);
            }
            (void)__hip_atomic_load(&g_sense, __ATOMIC_ACQUIRE,
                                    __HIP_MEMORY_SCOPE_AGENT);
        }
        __threadfence();
    }
    __syncthreads();

    // ---------------- A-operand: 32 W-rows per wave (r12 layout) ------------
    half8 wfr[16];
    {
        int grow = ((s31 >> 4) * 256) + wv * 16 + (s31 & 15);
        const _Float16* wp = &g_W[grow * 256 + hi * 8];
#pragma unroll
        for (int t = 0; t < 16; ++t)
            wfr[t] = *(const half8*)(wp + t * 16);
    }

    // ---------------- main loop: 4 groups x 64 samples, 1 barrier/group -----
    for (int g = 0; g < 4; ++g) {
        const int abase = (g & 1) ? A1_OFF : A0_OFF;
        const int pbase = (g & 1) ? P1_OFF : P0_OFF;

        if (g < 3) {
            const int nbase = (g & 1) ? A0_OFF : A1_OFF;
            stage_a(smem, x, bid * 256 + (g + 1) * 64, nbase, 0, tid);
            stage_a(smem, x, bid * 256 + (g + 1) * 64 + 32, nbase, 32, tid);
        }

        // ---- two 32x32 tiles SEQUENTIAL (r18) ----
#pragma unroll
        for (int t2 = 0; t2 < 2; ++t2) {
            const int row = t2 * 32 + s31;
            const int rowb = abase + row * 512;
            const int swz = (row & 31) << 4;   // full-width swizzle (r18)
            f32x16 acc = {0.f, 0.f, 0.f, 0.f, 0.f, 0.f, 0.f, 0.f,
                          0.f, 0.f, 0.f, 0.f, 0.f, 0.f, 0.f, 0.f};
#pragma unroll
            for (int t = 0; t < 16; ++t) {
                half8 bfr = *(const half8*)(smem + rowb + ((t * 32 + hi * 16) ^ swz));
                acc = __builtin_amdgcn_mfma_f32_32x32x16_f16(wfr[t], bfr, acc, 0, 0, 0);
            }

            // ---- epilogue: p in-lane, subset-sum sign reduce, permlane xor32 ----
            float p0 = acc[0] * acc[0] + acc[8] * acc[8];
            float p1 = acc[1] * acc[1] + acc[9] * acc[9];
            float p2 = acc[2] * acc[2] + acc[10] * acc[10];
            float p3 = acc[3] * acc[3] + acc[11] * acc[11];
            float p4 = acc[4] * acc[4] + acc[12] * acc[12];
            float p5 = acc[5] * acc[5] + acc[13] * acc[13];
            float p6 = acc[6] * acc[6] + acc[14] * acc[14];
            float p7 = acc[7] * acc[7] + acc[15] * acc[15];
            float a01 = p0 + p1, a23 = p2 + p3, a45 = p4 + p5, a67 = p6 + p7;
            float b03 = a01 + a23, b47 = a45 + a67;
            float S = b03 + b47;
            float E[8];
            E[0] = ((wv >> 3) & 1) ? -S : S;
            E[1] = ((wv >> 2) & 1) ? -S : S;
            E[2] = ((wv >> 1) & 1) ? -S : S;
            E[3] = (wv & 1) ? -S : S;
            E[4] = b03 - b47;
            E[5] = hi ? -S : S;
            E[6] = (a01 - a23) + (a45 - a67);
            E[7] = (p0 - p1) + (p2 - p3) + ((p4 - p5) + (p6 - p7));
#pragma unroll
            for (int q = 0; q < 8; ++q)
                E[q] += xor32(E[q], lane);
            if (hi == 0) {
                *(f32x4*)(smem + pbase + wv * 2080 + row * 32) = (f32x4){E[0], E[1], E[2], E[3]};
                *(f32x4*)(smem + pbase + wv * 2080 + row * 32 + 16) = (f32x4){E[4], E[5], E[6], E[7]};
            }
        }
        __syncthreads();   // PART[g&1] ready AND A[(g+1)&1] ready

        // ---- cross-wave sum + store (overlaps next section) ----
        if (tid < 512) {
            int s2 = tid >> 3, q = tid & 7;
            const char* pb = smem + pbase + s2 * 32 + q * 4;
            float sum = 0.f;
#pragma unroll
            for (int w = 0; w < 16; ++w)
                sum += *(const float*)(pb + w * 2080);
            out[(bid * 256 + g * 64 + s2) * 8 + q] = sum;
        }
    }
}

extern "C" void kernel_launch(void* const* d_in, const int* in_sizes, int n_in,
                              void* d_out, int out_size, void* d_ws, size_t ws_size,
                              hipStream_t stream) {
    const float* x = (const float*)d_in[0];       // (65536, 8) f32
    const float* wt = (const float*)d_in[1];      // (8, 8, 2) f32
    float* out = (float*)d_out;                   // (65536, 8) f32
    (void)d_ws; (void)ws_size; (void)in_sizes; (void)n_in; (void)out_size;

    fused<<<NBLK, 1024, 0, stream>>>(x, wt, out);
}